// Round 16
// baseline (1701.554 us; speedup 1.0000x reference)
//
#include <hip/hip_runtime.h>
#include <hip/hip_bf16.h>
#include <type_traits>

typedef __hip_bfloat16 bf16;
typedef short v8s __attribute__((ext_vector_type(8)));
typedef short v2s __attribute__((ext_vector_type(2)));
typedef float v4f __attribute__((ext_vector_type(4)));

__device__ __forceinline__ float b2f(bf16 v) { return __bfloat162float(v); }
__device__ __forceinline__ bf16  f2b(float v) { return __float2bfloat16(v); }
__device__ __forceinline__ short f2bs(float v) {
    bf16 b = f2b(v); short s; __builtin_memcpy(&s, &b, 2); return s;
}
__device__ __forceinline__ float bs2f(short s) {
    bf16 b; __builtin_memcpy(&b, &s, 2); return b2f(b);
}

#define NB 128
#define NN 128
#define KNN 16
#define M_NODES (NB * NN)          // 16384
#define NPOS ((long)M_NODES * KNN) // 262144 edge rows
#define NREP 16                    // stats replicas

__device__ __forceinline__ void fold_stats(const float* __restrict__ st, int c,
                                           float& sum, float& sq) {
    sum = 0.f; sq = 0.f;
#pragma unroll
    for (int r = 0; r < NREP; ++r) { sum += st[r * 512 + c]; sq += st[r * 512 + 256 + c]; }
}

// XCD batch-affinity swizzle. TPB tiles per batch; slot->XCD assumed round-robin.
template<int TPB>
__device__ __forceinline__ int swz_tile(int bid) {
    int xcd = bid & 7;
    int slot = bid >> 3;
    int batch = xcd * 16 + slot / TPB;
    int tile = slot - (slot / TPB) * TPB;
    return batch * TPB + tile;
}

// ---------------- fused prep: zero stats + weight precompute ----------------
__global__ __launch_bounds__(256) void prep_kernel(
    const float* __restrict__ W0, const float* __restrict__ W1, const float* __restrict__ W2,
    short* __restrict__ W0d, short* __restrict__ W0b,
    short* __restrict__ W1b, short* __restrict__ W2b,
    float* __restrict__ stats, int F, int Fpad, int O)
{
    int i = blockIdx.x * 256 + threadIdx.x;
    const int nz = 3 * NREP * 512;
    if (i < nz) { stats[i] = 0.f; return; }
    i -= nz;
    const int n0 = O * Fpad;
    if (i < n0) {
        int c = i / Fpad, k = i - c * Fpad;
        if (k < F) {
            float wt = W0[(size_t)k * O + c];
            float wb = W0[(size_t)(F + k) * O + c];
            W0d[i] = f2bs(wt - wb);
            W0b[i] = f2bs(wb);
        } else { W0d[i] = 0; W0b[i] = 0; }
        return;
    }
    i -= n0;
    const int n1 = O * O;
    if (i < n1) {
        int c = i / O, k = i - c * O;
        W1b[i] = f2bs(W1[(size_t)k * O + c]);
        return;
    }
    i -= n1;
    if (i < n1) {
        int c = i / O, k = i - c * O;
        W2b[i] = f2bs(W2[(size_t)k * O + c]);
    }
}

// ---------------- fused kNN: d2 in LDS + top-16 select, one block per batch ----------
// d2 math and accumulation order identical to the prior dist_kernel (inline norms),
// selection identical to the prior knn_select (ties -> lower j) => bit-identical idx.
__global__ __launch_bounds__(256) void knn_fused_kernel(const float* __restrict__ x,
        int C, int D, int* __restrict__ idx) {
    __shared__ float d2s[128][128];
    __shared__ float As[16][65];
    __shared__ float Bs[16][65];
    const int tid = threadIdx.x;
    const int tx = tid & 15, ty = tid >> 4;
    const int b = blockIdx.x;
#pragma unroll
    for (int tr = 0; tr < 2; ++tr)
#pragma unroll
        for (int tc = 0; tc < 2; ++tc) {
            const int m0 = b * NN + tr * 64;
            const int c0 = tc * 64;
            float acc[4][4], rn[4], cn[4];
#pragma unroll
            for (int r = 0; r < 4; ++r) { rn[r] = 0.f; cn[r] = 0.f;
#pragma unroll
                for (int c = 0; c < 4; ++c) acc[r][c] = 0.f; }
            for (int k0 = 0; k0 < D; k0 += 16) {
                __syncthreads();
                for (int l = tid; l < 1024; l += 256) {
                    int k = l & 15, m = l >> 4;
                    int kk = k0 + k;
                    As[k][m] = (kk < D) ? x[(size_t)(m0 + m) * C + kk] : 0.f;
                    Bs[k][m] = (kk < D) ? x[(size_t)(b * NN + c0 + m) * C + kk] : 0.f;
                }
                __syncthreads();
                for (int k = 0; k < 16; ++k) {
                    float av[4], bv[4];
#pragma unroll
                    for (int r = 0; r < 4; ++r) { av[r] = As[k][ty + 16 * r]; rn[r] += av[r] * av[r]; }
#pragma unroll
                    for (int c = 0; c < 4; ++c) { bv[c] = Bs[k][tx + 16 * c]; cn[c] += bv[c] * bv[c]; }
#pragma unroll
                    for (int r = 0; r < 4; ++r)
#pragma unroll
                        for (int c = 0; c < 4; ++c) acc[r][c] += av[r] * bv[c];
                }
            }
#pragma unroll
            for (int r = 0; r < 4; ++r)
#pragma unroll
                for (int c = 0; c < 4; ++c) {
                    int row = tr * 64 + ty + 16 * r;      // node within batch
                    int col = c0 + tx + 16 * c;
                    float v = rn[r] + cn[c] - 2.0f * acc[r][c];
                    if (row == col) v += 1e9f;
                    d2s[row][col] = v;
                }
        }
    __syncthreads();
    // selection: wave w handles nodes w*32 .. w*32+31
    const int lane = tid & 63, wave = tid >> 6;
    for (int i = 0; i < 32; ++i) {
        const int node = wave * 32 + i;
        float v0 = d2s[node][lane], v1 = d2s[node][lane + 64];
        int j0 = lane, j1 = lane + 64;
        int myIdx = 0;
#pragma unroll
        for (int k = 0; k < KNN; ++k) {
            float bv; int bj;
            if (v1 < v0 || (v1 == v0 && j1 < j0)) { bv = v1; bj = j1; }
            else                                 { bv = v0; bj = j0; }
#pragma unroll
            for (int off = 32; off; off >>= 1) {
                float ov = __shfl_xor(bv, off);
                int oj = __shfl_xor(bj, off);
                if (ov < bv || (ov == bv && oj < bj)) { bv = ov; bj = oj; }
            }
            if (bj == j0) v0 = 3.0e38f;
            if (bj == j1) v1 = 3.0e38f;
            if (lane == k) myIdx = bj;
        }
        if (lane < KNN) idx[(size_t)(b * NN + node) * KNN + lane] = myIdx;
    }
}

// ---------------- MFMA node GEMM: T1 = x@Wd + bias, T2 = x@Wb ----------------
template<int O>
__global__ __launch_bounds__(256, 2) void node_gemm_mfma(
    const float* __restrict__ x, int F, int Fpad,
    const short* __restrict__ Wd, const short* __restrict__ Wb,
    const float* __restrict__ bias,
    float* __restrict__ T1, float* __restrict__ T2)
{
    constexpr int CPW = O / 64;
    __shared__ __align__(16) short Am[64][232];
    const int tid = threadIdx.x;
    const int lane = tid & 63, wave = tid >> 6;
    const int l15 = lane & 15, quad = lane >> 4;
    const int m0 = blockIdx.x * 64;
    for (int l = tid; l < 64 * Fpad; l += 256) {
        int m = l / Fpad, k = l - m * Fpad;
        Am[m][k] = (k < F) ? f2bs(x[(size_t)(m0 + m) * F + k]) : (short)0;
    }
    __syncthreads();
#pragma unroll
    for (int p = 0; p < 2; ++p) {
        const short* __restrict__ Wg = p ? Wb : Wd;
        float* __restrict__ T = p ? T2 : T1;
        v4f acc[4][CPW];
#pragma unroll
        for (int rt = 0; rt < 4; ++rt)
#pragma unroll
            for (int j = 0; j < CPW; ++j)
#pragma unroll
                for (int r = 0; r < 4; ++r) acc[rt][j][r] = 0.f;
        for (int k0 = 0; k0 < Fpad; k0 += 32) {
#pragma unroll
            for (int rt = 0; rt < 4; ++rt) {
                v8s av = *(const v8s*)&Am[rt * 16 + l15][k0 + quad * 8];
#pragma unroll
                for (int j = 0; j < CPW; ++j) {
                    int c = (wave * CPW + j) * 16 + l15;
                    v8s bv = *(const v8s*)&Wg[(size_t)c * Fpad + k0 + quad * 8];
                    acc[rt][j] = __builtin_amdgcn_mfma_f32_16x16x32_bf16(av, bv, acc[rt][j], 0, 0, 0);
                }
            }
        }
#pragma unroll
        for (int j = 0; j < CPW; ++j) {
            int c = (wave * CPW + j) * 16 + l15;
            float bb = p ? 0.f : bias[c];
#pragma unroll
            for (int rt = 0; rt < 4; ++rt)
#pragma unroll
                for (int r = 0; r < 4; ++r)
                    T[(size_t)(m0 + rt * 16 + quad * 4 + r) * O + c] = acc[rt][j][r] + bb;
        }
    }
}

// ---------------- stats0: LDS-staged per-batch ----------------
template<int O>
__global__ __launch_bounds__(256) void stats0_lds_kernel(
    const float* __restrict__ T1, const float* __restrict__ T2,
    const int* __restrict__ idx, float* __restrict__ st0)
{
    constexpr int CH = (O > 128) ? 128 : O;
    constexpr int NG = 256 / CH;
    constexpr int NPG = NN / NG;
    __shared__ float T2s[NN][CH];
    __shared__ int idxs[NN * KNN];
    __shared__ float redS[NG][CH], redQ[NG][CH];
    const int tid = threadIdx.x;
    const int nchunk = O / CH;
    const int b = blockIdx.x / nchunk;
    const int c0 = (blockIdx.x - b * nchunk) * CH;
    const int rep = blockIdx.x & (NREP - 1);

    for (int l = tid; l < NN * CH; l += 256) {
        int n = l / CH, c = l - n * CH;
        T2s[n][c] = T2[(size_t)(b * NN + n) * O + c0 + c];
    }
    for (int l = tid; l < NN * KNN; l += 256) idxs[l] = idx[(size_t)b * NN * KNN + l];
    __syncthreads();

    const int c = tid & (CH - 1);
    const int g = tid / CH;
    float s = 0.f, q = 0.f;
    for (int n = g * NPG; n < (g + 1) * NPG; ++n) {
        float t1 = T1[(size_t)(b * NN + n) * O + c0 + c];
#pragma unroll
        for (int k = 0; k < KNN; ++k) {
            int j = idxs[n * KNN + k];
            float v = t1 + T2s[j][c];
            s += v; q += v * v;
        }
    }
    redS[g][c] = s; redQ[g][c] = q;
    __syncthreads();
    if (g == 0) {
#pragma unroll
        for (int gg = 1; gg < NG; ++gg) { s += redS[gg][c]; q += redQ[gg][c]; }
        atomicAdd(&st0[rep * 512 + c0 + c], s);
        atomicAdd(&st0[rep * 512 + 256 + c0 + c], q);
    }
}

// ========================= column-owned MFMA GEMM kernels ==========================
// ROWS = 8192/O (occupancy-optimized); wave owns O/4 cols for all ROWS rows.

// ---------------- gemm1: A0-build -> h1 = A0@W1 + b1 -> h + st1 ----------------
template<int O, int ROWS>
__global__ __launch_bounds__(256, 6) void gemm1_kernel(
    const float* __restrict__ T1, const float* __restrict__ T2, const int* __restrict__ idx,
    const short* __restrict__ W1, const float* __restrict__ bias1,
    const float* __restrict__ gm0, const float* __restrict__ bt0,
    const float* __restrict__ st0, float* __restrict__ st1,
    short* __restrict__ h, float inv_n)
{
    constexpr int CPW = O / 64;
    constexpr int RT = ROWS / 16;
    constexpr int OSH = (O == 64) ? 6 : (O == 128 ? 7 : 8);
    constexpr int AP = O + 8;
    constexpr int TPB = 2048 / ROWS;
    __shared__ __align__(16) short Am[ROWS][AP];
    __shared__ float sc0[O], sh0[O];
    __shared__ int gArr[ROWS];
    const int tid = threadIdx.x;
    const int lane = tid & 63, wave = tid >> 6;
    const int l15 = lane & 15, quad = lane >> 4;
    const int work = swz_tile<TPB>(blockIdx.x);
    const int e0 = work * ROWS;
    const int nb0 = e0 >> 4;
    const int rep = work & (NREP - 1);

    for (int l = tid; l < ROWS; l += 256) {
        int e = e0 + l;
        int nd = e >> 4;
        gArr[l] = ((nd >> 7) << 7) + idx[e];
    }
    if (tid < O) {
        float sum, sq;
        fold_stats(st0, tid, sum, sq);
        float mean = sum * inv_n;
        float var = fmaxf(sq * inv_n - mean * mean, 0.f);
        float s = rsqrtf(var + 1e-5f) * gm0[tid];
        sc0[tid] = s; sh0[tid] = bt0[tid] - mean * s;
    }
    __syncthreads();

    for (int l = tid; l < ROWS * O / 2; l += 256) {
        int m = l >> (OSH - 1);
        int c = (l & (O / 2 - 1)) * 2;
        const float2 t1 = *(const float2*)&T1[(size_t)(nb0 + (m >> 4)) * O + c];
        const float2 t2 = *(const float2*)&T2[(size_t)gArr[m] * O + c];
        float v0 = fmaxf((t1.x + t2.x) * sc0[c] + sh0[c], 0.f);
        float v1 = fmaxf((t1.y + t2.y) * sc0[c + 1] + sh0[c + 1], 0.f);
        v2s pr; pr[0] = f2bs(v0); pr[1] = f2bs(v1);
        *(v2s*)&Am[m][c] = pr;
    }
    __syncthreads();

    v4f acc[RT][CPW];
#pragma unroll
    for (int rt = 0; rt < RT; ++rt)
#pragma unroll
        for (int j = 0; j < CPW; ++j)
#pragma unroll
            for (int r = 0; r < 4; ++r) acc[rt][j][r] = 0.f;

#pragma unroll
    for (int k0 = 0; k0 < O; k0 += 32) {
        v8s bv[CPW];
#pragma unroll
        for (int j = 0; j < CPW; ++j) {
            int c = (wave * CPW + j) * 16 + l15;
            bv[j] = *(const v8s*)&W1[(size_t)c * O + k0 + quad * 8];
        }
#pragma unroll
        for (int rt = 0; rt < RT; ++rt) {
            v8s av = *(const v8s*)&Am[rt * 16 + l15][k0 + quad * 8];
#pragma unroll
            for (int j = 0; j < CPW; ++j)
                acc[rt][j] = __builtin_amdgcn_mfma_f32_16x16x32_bf16(av, bv[j], acc[rt][j], 0, 0, 0);
        }
    }
#pragma unroll
    for (int j = 0; j < CPW; ++j) {
        float bb = bias1[(wave * CPW + j) * 16 + l15];
#pragma unroll
        for (int rt = 0; rt < RT; ++rt)
#pragma unroll
            for (int r = 0; r < 4; ++r) acc[rt][j][r] += bb;
    }
#pragma unroll
    for (int j = 0; j < CPW; ++j) {
        int c = (wave * CPW + j) * 16 + l15;
        float s = 0.f, q = 0.f;
#pragma unroll
        for (int rt = 0; rt < RT; ++rt)
#pragma unroll
            for (int r = 0; r < 4; ++r) { float v = acc[rt][j][r]; s += v; q += v * v; }
        s += __shfl_down(s, 32); s += __shfl_down(s, 16);
        q += __shfl_down(q, 32); q += __shfl_down(q, 16);
        if (quad == 0) { atomicAdd(&st1[rep * 512 + c], s); atomicAdd(&st1[rep * 512 + 256 + c], q); }
    }
    __syncthreads();
#pragma unroll
    for (int j = 0; j < CPW; ++j) {
        int c = (wave * CPW + j) * 16 + l15;
#pragma unroll
        for (int rt = 0; rt < RT; ++rt)
#pragma unroll
            for (int r = 0; r < 4; ++r)
                Am[rt * 16 + quad * 4 + r][c] = f2bs(acc[rt][j][r]);
    }
    __syncthreads();
    for (int g = tid; g < ROWS * O / 8; g += 256) {
        int row = g >> (OSH - 3);
        int c8 = (g & (O / 8 - 1)) * 8;
        *(v8s*)&h[(size_t)(e0 + row) * O + c8] = *(const v8s*)&Am[row][c8];
    }
}

// ---------------- gemm2: h -> bn1+relu -> h2 = A1@W2 + b2 -> h (in place) + st2 ------
template<int O, int ROWS>
__global__ __launch_bounds__(256, 6) void gemm2_kernel(
    short* __restrict__ h,
    const short* __restrict__ W2, const float* __restrict__ bias2,
    const float* __restrict__ gm1, const float* __restrict__ bt1,
    const float* __restrict__ st1, float* __restrict__ st2, float inv_n)
{
    constexpr int CPW = O / 64;
    constexpr int RT = ROWS / 16;
    constexpr int OSH = (O == 64) ? 6 : (O == 128 ? 7 : 8);
    constexpr int AP = O + 8;
    constexpr int TPB = 2048 / ROWS;
    __shared__ __align__(16) short Am[ROWS][AP];
    __shared__ float sc1[O], sh1[O];
    const int tid = threadIdx.x;
    const int lane = tid & 63, wave = tid >> 6;
    const int l15 = lane & 15, quad = lane >> 4;
    const int work = swz_tile<TPB>(blockIdx.x);
    const int e0 = work * ROWS;
    const int rep = work & (NREP - 1);

    if (tid < O) {
        float sum, sq;
        fold_stats(st1, tid, sum, sq);
        float mean = sum * inv_n;
        float var = fmaxf(sq * inv_n - mean * mean, 0.f);
        float s = rsqrtf(var + 1e-5f) * gm1[tid];
        sc1[tid] = s; sh1[tid] = bt1[tid] - mean * s;
    }
    __syncthreads();

    for (int g = tid; g < ROWS * O / 8; g += 256) {
        int row = g >> (OSH - 3);
        int c8 = (g & (O / 8 - 1)) * 8;
        v8s hv = *(const v8s*)&h[(size_t)(e0 + row) * O + c8];
        v8s ov;
#pragma unroll
        for (int j = 0; j < 8; ++j) {
            float v = bs2f(hv[j]) * sc1[c8 + j] + sh1[c8 + j];
            ov[j] = f2bs(fmaxf(v, 0.f));
        }
        *(v8s*)&Am[row][c8] = ov;
    }
    __syncthreads();

    v4f acc[RT][CPW];
#pragma unroll
    for (int rt = 0; rt < RT; ++rt)
#pragma unroll
        for (int j = 0; j < CPW; ++j)
#pragma unroll
            for (int r = 0; r < 4; ++r) acc[rt][j][r] = 0.f;

#pragma unroll
    for (int k0 = 0; k0 < O; k0 += 32) {
        v8s bv[CPW];
#pragma unroll
        for (int j = 0; j < CPW; ++j) {
            int c = (wave * CPW + j) * 16 + l15;
            bv[j] = *(const v8s*)&W2[(size_t)c * O + k0 + quad * 8];
        }
#pragma unroll
        for (int rt = 0; rt < RT; ++rt) {
            v8s av = *(const v8s*)&Am[rt * 16 + l15][k0 + quad * 8];
#pragma unroll
            for (int j = 0; j < CPW; ++j)
                acc[rt][j] = __builtin_amdgcn_mfma_f32_16x16x32_bf16(av, bv[j], acc[rt][j], 0, 0, 0);
        }
    }
#pragma unroll
    for (int j = 0; j < CPW; ++j) {
        float bb = bias2[(wave * CPW + j) * 16 + l15];
#pragma unroll
        for (int rt = 0; rt < RT; ++rt)
#pragma unroll
            for (int r = 0; r < 4; ++r) acc[rt][j][r] += bb;
    }
#pragma unroll
    for (int j = 0; j < CPW; ++j) {
        int c = (wave * CPW + j) * 16 + l15;
        float s = 0.f, q = 0.f;
#pragma unroll
        for (int rt = 0; rt < RT; ++rt)
#pragma unroll
            for (int r = 0; r < 4; ++r) { float v = acc[rt][j][r]; s += v; q += v * v; }
        s += __shfl_down(s, 32); s += __shfl_down(s, 16);
        q += __shfl_down(q, 32); q += __shfl_down(q, 16);
        if (quad == 0) { atomicAdd(&st2[rep * 512 + c], s); atomicAdd(&st2[rep * 512 + 256 + c], q); }
    }
    __syncthreads();
#pragma unroll
    for (int j = 0; j < CPW; ++j) {
        int c = (wave * CPW + j) * 16 + l15;
#pragma unroll
        for (int rt = 0; rt < RT; ++rt)
#pragma unroll
            for (int r = 0; r < 4; ++r)
                Am[rt * 16 + quad * 4 + r][c] = f2bs(acc[rt][j][r]);
    }
    __syncthreads();
    for (int g = tid; g < ROWS * O / 8; g += 256) {
        int row = g >> (OSH - 3);
        int c8 = (g & (O / 8 - 1)) * 8;
        *(v8s*)&h[(size_t)(e0 + row) * O + c8] = *(const v8s*)&Am[row][c8];
    }
}

// ---------------- finish: stream h2, bn2+relu, k-mean, skip-concat ----------------
template<int O, int ROWS>
__global__ __launch_bounds__(256) void finish_kernel(
    const short* __restrict__ h,
    const float* __restrict__ st2, const float* __restrict__ gm2, const float* __restrict__ bt2,
    const float* __restrict__ xold, float* __restrict__ xnew, int F, float inv_n)
{
    constexpr int G = 256 / O;
    constexpr int RPG = ROWS / G;
    constexpr int NPG = RPG / 16;
    constexpr int NPB = ROWS / 16;
    constexpr int TPB = 2048 / ROWS;
    const int tid = threadIdx.x;
    const int c = tid & (O - 1);
    const int rg = tid / O;
    const int work = swz_tile<TPB>(blockIdx.x);
    const int e0 = work * ROWS;
    const int nb0 = e0 >> 4;
    float sum, sq;
    fold_stats(st2, c, sum, sq);
    float mean = sum * inv_n;
    float var = fmaxf(sq * inv_n - mean * mean, 0.f);
    float sc = rsqrtf(var + 1e-5f) * gm2[c];
    float sh = bt2[c] - mean * sc;
    float s[NPG];
#pragma unroll
    for (int i = 0; i < NPG; ++i) s[i] = 0.f;
    const int m0 = rg * RPG;
#pragma unroll
    for (int r = 0; r < RPG; ++r) {
        float v = bs2f(h[(size_t)(e0 + m0 + r) * O + c]) * sc + sh;
        s[r >> 4] += fmaxf(v, 0.f);
    }
    const int Cnew = O + F;
#pragma unroll
    for (int i = 0; i < NPG; ++i)
        xnew[(size_t)(nb0 + rg * NPG + i) * Cnew + c] = s[i] * (1.0f / 16.0f);
    for (int l = tid; l < NPB * F; l += 256) {
        int nd = l / F, cc = l - nd * F;
        xnew[(size_t)(nb0 + nd) * Cnew + O + cc] = xold[(size_t)(nb0 + nd) * F + cc];
    }
}

// ---------------- global mean pool ----------------
__global__ __launch_bounds__(256) void pool_kernel(const float* __restrict__ x, float* __restrict__ pooled, int C) {
    int b = blockIdx.x, t = threadIdx.x;
    for (int c = t; c < C; c += 256) {
        float s = 0.f;
        for (int n = 0; n < NN; ++n) s += x[(size_t)(b * NN + n) * C + c];
        pooled[b * C + c] = s * (1.0f / NN);
    }
}

// ---------------- fc1 + fc2 ----------------
__global__ __launch_bounds__(256) void fc_kernel(const float* __restrict__ pooled,
                                                 const float* __restrict__ W1, const float* __restrict__ b1,
                                                 const float* __restrict__ W2, const float* __restrict__ b2,
                                                 float* __restrict__ out, int C) {
    __shared__ float px[451];
    __shared__ float h1[256];
    int b = blockIdx.x, t = threadIdx.x;
    for (int c = t; c < C; c += 256) px[c] = pooled[b * C + c];
    __syncthreads();
    float s = 0.f;
    for (int i = 0; i < C; ++i) s += px[i] * W1[(size_t)i * 256 + t];
    h1[t] = s + b1[t];
    __syncthreads();
    if (t < 5) {
        float s2 = 0.f;
        for (int j = 0; j < 256; ++j) s2 += h1[j] * W2[j * 5 + t];
        out[b * 5 + t] = s2 + b2[t];
    }
}

extern "C" void kernel_launch(void* const* d_in, const int* in_sizes, int n_in,
                              void* d_out, int out_size, void* d_ws, size_t ws_size,
                              hipStream_t stream) {
    const float* xin = (const float*)d_in[0];
    auto Wp = [&](int c, int l) { return (const float*)d_in[1 + c * 12 + l * 4 + 0]; };
    auto Bp = [&](int c, int l) { return (const float*)d_in[1 + c * 12 + l * 4 + 1]; };
    auto Gp = [&](int c, int l) { return (const float*)d_in[1 + c * 12 + l * 4 + 2]; };
    auto Ep = [&](int c, int l) { return (const float*)d_in[1 + c * 12 + l * 4 + 3]; };
    const float* fcW1 = (const float*)d_in[37];
    const float* fcb1 = (const float*)d_in[38];
    const float* fcW2 = (const float*)d_in[39];
    const float* fcb2 = (const float*)d_in[40];

    char* ws = (char*)d_ws;
    size_t off = 0;
    auto alloc = [&](size_t bytes) -> void* {
        void* p = ws + off;
        off += (bytes + 255) & ~(size_t)255;
        return p;
    };
    const int M = M_NODES;
    float* x1     = (float*)alloc((size_t)M * 67 * 4);
    float* x2     = (float*)alloc((size_t)M * 195 * 4);
    float* x3     = (float*)alloc((size_t)M * 451 * 4);
    float* T1     = (float*)alloc((size_t)M * 256 * 4);
    float* T2     = (float*)alloc((size_t)M * 256 * 4);
    int*   idxb   = (int*)alloc((size_t)M * KNN * 4);
    float* stats  = (float*)alloc((size_t)3 * NREP * 512 * 4);
    float* pooled = (float*)alloc((size_t)NB * 451 * 4);
    short* W1b    = (short*)alloc(256 * 256 * 2);
    short* W2b    = (short*)alloc(256 * 256 * 2);
    short* W0d    = (short*)alloc(256 * 224 * 2);
    short* W0b    = (short*)alloc(256 * 224 * 2);
    short* hbuf   = (short*)alloc((size_t)NPOS * 256 * 2);
    (void)in_sizes; (void)n_in; (void)out_size; (void)ws_size;

    float* st0 = stats;
    float* st1 = stats + NREP * 512;
    float* st2 = stats + 2 * NREP * 512;
    const float inv_n = 1.0f / (float)NPOS;

    auto run_conv = [&](const float* xc, float* xn, int F, int D, int O, int c) {
        const int Fpad = (F + 31) & ~31;
        knn_fused_kernel<<<NB, 256, 0, stream>>>(xc, F, D, idxb);
        const int prepN = 3 * NREP * 512 + O * Fpad + 2 * O * O;
        prep_kernel<<<(prepN + 255) / 256, 256, 0, stream>>>(Wp(c, 0), Wp(c, 1), Wp(c, 2),
            W0d, W0b, W1b, W2b, stats, F, Fpad, O);
        auto launch = [&](auto tag) {
            constexpr int OO = decltype(tag)::value;
            constexpr int RR = 8192 / OO;         // 128/64/32 rows per tile
            const int grid = (int)(NPOS / RR);
            node_gemm_mfma<OO><<<M / 64, 256, 0, stream>>>(xc, F, Fpad, W0d, W0b, Bp(c, 0), T1, T2);
            stats0_lds_kernel<OO><<<NB * (OO > 128 ? 2 : 1), 256, 0, stream>>>(T1, T2, idxb, st0);
            gemm1_kernel<OO, RR><<<grid, 256, 0, stream>>>(T1, T2, idxb, W1b, Bp(c, 1),
                Gp(c, 0), Ep(c, 0), st0, st1, hbuf, inv_n);
            gemm2_kernel<OO, RR><<<grid, 256, 0, stream>>>(hbuf, W2b, Bp(c, 2),
                Gp(c, 1), Ep(c, 1), st1, st2, inv_n);
            finish_kernel<OO, RR><<<grid, 256, 0, stream>>>(hbuf, st2, Gp(c, 2), Ep(c, 2),
                xc, xn, F, inv_n);
        };
        if (O == 64)       launch(std::integral_constant<int, 64>{});
        else if (O == 128) launch(std::integral_constant<int, 128>{});
        else               launch(std::integral_constant<int, 256>{});
    };

    run_conv(xin, x1, 3, 2, 64, 0);     // -> x1: C=67
    run_conv(x1, x2, 67, 67, 128, 1);   // -> x2: C=195
    run_conv(x2, x3, 195, 195, 256, 2); // -> x3: C=451
    pool_kernel<<<NB, 256, 0, stream>>>(x3, pooled, 451);
    fc_kernel<<<NB, 256, 0, stream>>>(pooled, fcW1, fcb1, fcW2, fcb2, (float*)d_out, 451);
}

// Round 17
// 982.271 us; speedup vs baseline: 1.7323x; 1.7323x over previous
//
#include <hip/hip_runtime.h>
#include <hip/hip_bf16.h>
#include <type_traits>

typedef __hip_bfloat16 bf16;
typedef short v8s __attribute__((ext_vector_type(8)));
typedef short v2s __attribute__((ext_vector_type(2)));
typedef float v4f __attribute__((ext_vector_type(4)));

__device__ __forceinline__ float b2f(bf16 v) { return __bfloat162float(v); }
__device__ __forceinline__ bf16  f2b(float v) { return __float2bfloat16(v); }
__device__ __forceinline__ short f2bs(float v) {
    bf16 b = f2b(v); short s; __builtin_memcpy(&s, &b, 2); return s;
}
__device__ __forceinline__ float bs2f(short s) {
    bf16 b; __builtin_memcpy(&b, &s, 2); return b2f(b);
}

#define NB 128
#define NN 128
#define KNN 16
#define M_NODES (NB * NN)          // 16384
#define NPOS ((long)M_NODES * KNN) // 262144 edge rows
#define NREP 16                    // stats replicas

__device__ __forceinline__ void fold_stats(const float* __restrict__ st, int c,
                                           float& sum, float& sq) {
    sum = 0.f; sq = 0.f;
#pragma unroll
    for (int r = 0; r < NREP; ++r) { sum += st[r * 512 + c]; sq += st[r * 512 + 256 + c]; }
}

// XCD batch-affinity swizzle. TPB tiles per batch; slot->XCD assumed round-robin.
template<int TPB>
__device__ __forceinline__ int swz_tile(int bid) {
    int xcd = bid & 7;
    int slot = bid >> 3;
    int batch = xcd * 16 + slot / TPB;
    int tile = slot - (slot / TPB) * TPB;
    return batch * TPB + tile;
}

// ---------------- fused prep: zero stats + weight precompute ----------------
__global__ __launch_bounds__(256) void prep_kernel(
    const float* __restrict__ W0, const float* __restrict__ W1, const float* __restrict__ W2,
    short* __restrict__ W0d, short* __restrict__ W0b,
    short* __restrict__ W1b, short* __restrict__ W2b,
    float* __restrict__ stats, int F, int Fpad, int O)
{
    int i = blockIdx.x * 256 + threadIdx.x;
    const int nz = 3 * NREP * 512;
    if (i < nz) { stats[i] = 0.f; return; }
    i -= nz;
    const int n0 = O * Fpad;
    if (i < n0) {
        int c = i / Fpad, k = i - c * Fpad;
        if (k < F) {
            float wt = W0[(size_t)k * O + c];
            float wb = W0[(size_t)(F + k) * O + c];
            W0d[i] = f2bs(wt - wb);
            W0b[i] = f2bs(wb);
        } else { W0d[i] = 0; W0b[i] = 0; }
        return;
    }
    i -= n0;
    const int n1 = O * O;
    if (i < n1) {
        int c = i / O, k = i - c * O;
        W1b[i] = f2bs(W1[(size_t)k * O + c]);
        return;
    }
    i -= n1;
    if (i < n1) {
        int c = i / O, k = i - c * O;
        W2b[i] = f2bs(W2[(size_t)k * O + c]);
    }
}

// ---------------- kNN: d2 tile GEMM with inline norms (full-occupancy grid) ----------
__global__ __launch_bounds__(256) void dist_kernel(const float* __restrict__ x, int C, int D,
                                                   float* __restrict__ d2) {
    __shared__ float As[16][65];
    __shared__ float Bs[16][65];
    const int tid = threadIdx.x;
    const int tx = tid & 15, ty = tid >> 4;
    const int m0 = blockIdx.y * 64;
    const int b  = m0 >> 7;
    const int c0 = blockIdx.x * 64;
    float acc[4][4], rn[4], cn[4];
#pragma unroll
    for (int r = 0; r < 4; ++r) { rn[r] = 0.f; cn[r] = 0.f;
#pragma unroll
        for (int c = 0; c < 4; ++c) acc[r][c] = 0.f; }
    for (int k0 = 0; k0 < D; k0 += 16) {
        for (int l = tid; l < 1024; l += 256) {
            int k = l & 15, m = l >> 4;
            int kk = k0 + k;
            As[k][m] = (kk < D) ? x[(size_t)(m0 + m) * C + kk] : 0.f;
            Bs[k][m] = (kk < D) ? x[(size_t)(b * NN + c0 + m) * C + kk] : 0.f;
        }
        __syncthreads();
        for (int k = 0; k < 16; ++k) {
            float av[4], bv[4];
#pragma unroll
            for (int r = 0; r < 4; ++r) { av[r] = As[k][ty + 16 * r]; rn[r] += av[r] * av[r]; }
#pragma unroll
            for (int c = 0; c < 4; ++c) { bv[c] = Bs[k][tx + 16 * c]; cn[c] += bv[c] * bv[c]; }
#pragma unroll
            for (int r = 0; r < 4; ++r)
#pragma unroll
                for (int c = 0; c < 4; ++c) acc[r][c] += av[r] * bv[c];
        }
        __syncthreads();
    }
#pragma unroll
    for (int r = 0; r < 4; ++r)
#pragma unroll
        for (int c = 0; c < 4; ++c) {
            int m = m0 + ty + 16 * r;
            int jl = c0 + tx + 16 * c;
            int jg = b * NN + jl;
            float v = rn[r] + cn[c] - 2.0f * acc[r][c];
            if (m == jg) v += 1e9f;
            d2[(size_t)m * NN + jl] = v;
        }
}

// ---------------- kNN: wave-per-node top-16 ----------------
__global__ __launch_bounds__(256) void knn_select_kernel(const float* __restrict__ d2,
                                                         int* __restrict__ idx) {
    const int node = blockIdx.x * 4 + (threadIdx.x >> 6);
    const int lane = threadIdx.x & 63;
    const float* row = d2 + (size_t)node * NN;
    float v0 = row[lane], v1 = row[lane + 64];
    int j0 = lane, j1 = lane + 64;
    int myIdx = 0;
#pragma unroll
    for (int k = 0; k < KNN; ++k) {
        float bv; int bj;
        if (v1 < v0 || (v1 == v0 && j1 < j0)) { bv = v1; bj = j1; }
        else                                 { bv = v0; bj = j0; }
#pragma unroll
        for (int off = 32; off; off >>= 1) {
            float ov = __shfl_xor(bv, off);
            int oj = __shfl_xor(bj, off);
            if (ov < bv || (ov == bv && oj < bj)) { bv = ov; bj = oj; }
        }
        if (bj == j0) v0 = 3.0e38f;
        if (bj == j1) v1 = 3.0e38f;
        if (lane == k) myIdx = bj;
    }
    if (lane < KNN) idx[(size_t)node * KNN + lane] = myIdx;
}

// ---------------- MFMA node GEMM: T1 = x@Wd + bias, T2 = x@Wb ----------------
template<int O>
__global__ __launch_bounds__(256, 2) void node_gemm_mfma(
    const float* __restrict__ x, int F, int Fpad,
    const short* __restrict__ Wd, const short* __restrict__ Wb,
    const float* __restrict__ bias,
    float* __restrict__ T1, float* __restrict__ T2)
{
    constexpr int CPW = O / 64;
    __shared__ __align__(16) short Am[64][232];
    const int tid = threadIdx.x;
    const int lane = tid & 63, wave = tid >> 6;
    const int l15 = lane & 15, quad = lane >> 4;
    const int m0 = blockIdx.x * 64;
    for (int l = tid; l < 64 * Fpad; l += 256) {
        int m = l / Fpad, k = l - m * Fpad;
        Am[m][k] = (k < F) ? f2bs(x[(size_t)(m0 + m) * F + k]) : (short)0;
    }
    __syncthreads();
#pragma unroll
    for (int p = 0; p < 2; ++p) {
        const short* __restrict__ Wg = p ? Wb : Wd;
        float* __restrict__ T = p ? T2 : T1;
        v4f acc[4][CPW];
#pragma unroll
        for (int rt = 0; rt < 4; ++rt)
#pragma unroll
            for (int j = 0; j < CPW; ++j)
#pragma unroll
                for (int r = 0; r < 4; ++r) acc[rt][j][r] = 0.f;
        for (int k0 = 0; k0 < Fpad; k0 += 32) {
#pragma unroll
            for (int rt = 0; rt < 4; ++rt) {
                v8s av = *(const v8s*)&Am[rt * 16 + l15][k0 + quad * 8];
#pragma unroll
                for (int j = 0; j < CPW; ++j) {
                    int c = (wave * CPW + j) * 16 + l15;
                    v8s bv = *(const v8s*)&Wg[(size_t)c * Fpad + k0 + quad * 8];
                    acc[rt][j] = __builtin_amdgcn_mfma_f32_16x16x32_bf16(av, bv, acc[rt][j], 0, 0, 0);
                }
            }
        }
#pragma unroll
        for (int j = 0; j < CPW; ++j) {
            int c = (wave * CPW + j) * 16 + l15;
            float bb = p ? 0.f : bias[c];
#pragma unroll
            for (int rt = 0; rt < 4; ++rt)
#pragma unroll
                for (int r = 0; r < 4; ++r)
                    T[(size_t)(m0 + rt * 16 + quad * 4 + r) * O + c] = acc[rt][j][r] + bb;
        }
    }
}

// ---------------- stats0: LDS-staged per-batch ----------------
template<int O>
__global__ __launch_bounds__(256) void stats0_lds_kernel(
    const float* __restrict__ T1, const float* __restrict__ T2,
    const int* __restrict__ idx, float* __restrict__ st0)
{
    constexpr int CH = (O > 128) ? 128 : O;
    constexpr int NG = 256 / CH;
    constexpr int NPG = NN / NG;
    __shared__ float T2s[NN][CH];
    __shared__ int idxs[NN * KNN];
    __shared__ float redS[NG][CH], redQ[NG][CH];
    const int tid = threadIdx.x;
    const int nchunk = O / CH;
    const int b = blockIdx.x / nchunk;
    const int c0 = (blockIdx.x - b * nchunk) * CH;
    const int rep = blockIdx.x & (NREP - 1);

    for (int l = tid; l < NN * CH; l += 256) {
        int n = l / CH, c = l - n * CH;
        T2s[n][c] = T2[(size_t)(b * NN + n) * O + c0 + c];
    }
    for (int l = tid; l < NN * KNN; l += 256) idxs[l] = idx[(size_t)b * NN * KNN + l];
    __syncthreads();

    const int c = tid & (CH - 1);
    const int g = tid / CH;
    float s = 0.f, q = 0.f;
    for (int n = g * NPG; n < (g + 1) * NPG; ++n) {
        float t1 = T1[(size_t)(b * NN + n) * O + c0 + c];
#pragma unroll
        for (int k = 0; k < KNN; ++k) {
            int j = idxs[n * KNN + k];
            float v = t1 + T2s[j][c];
            s += v; q += v * v;
        }
    }
    redS[g][c] = s; redQ[g][c] = q;
    __syncthreads();
    if (g == 0) {
#pragma unroll
        for (int gg = 1; gg < NG; ++gg) { s += redS[gg][c]; q += redQ[gg][c]; }
        atomicAdd(&st0[rep * 512 + c0 + c], s);
        atomicAdd(&st0[rep * 512 + 256 + c0 + c], q);
    }
}

// ========================= column-owned MFMA GEMM kernels ==========================
// ROWS = 8192/O (occupancy-optimized); wave owns O/4 cols for all ROWS rows.

// ---------------- gemm1: A0-build -> h1 = A0@W1 + b1 -> h + st1 ----------------
template<int O, int ROWS>
__global__ __launch_bounds__(256, 6) void gemm1_kernel(
    const float* __restrict__ T1, const float* __restrict__ T2, const int* __restrict__ idx,
    const short* __restrict__ W1, const float* __restrict__ bias1,
    const float* __restrict__ gm0, const float* __restrict__ bt0,
    const float* __restrict__ st0, float* __restrict__ st1,
    short* __restrict__ h, float inv_n)
{
    constexpr int CPW = O / 64;
    constexpr int RT = ROWS / 16;
    constexpr int OSH = (O == 64) ? 6 : (O == 128 ? 7 : 8);
    constexpr int AP = O + 8;
    constexpr int TPB = 2048 / ROWS;
    __shared__ __align__(16) short Am[ROWS][AP];
    __shared__ float sc0[O], sh0[O];
    __shared__ int gArr[ROWS];
    const int tid = threadIdx.x;
    const int lane = tid & 63, wave = tid >> 6;
    const int l15 = lane & 15, quad = lane >> 4;
    const int work = swz_tile<TPB>(blockIdx.x);
    const int e0 = work * ROWS;
    const int nb0 = e0 >> 4;
    const int rep = work & (NREP - 1);

    for (int l = tid; l < ROWS; l += 256) {
        int e = e0 + l;
        int nd = e >> 4;
        gArr[l] = ((nd >> 7) << 7) + idx[e];
    }
    if (tid < O) {
        float sum, sq;
        fold_stats(st0, tid, sum, sq);
        float mean = sum * inv_n;
        float var = fmaxf(sq * inv_n - mean * mean, 0.f);
        float s = rsqrtf(var + 1e-5f) * gm0[tid];
        sc0[tid] = s; sh0[tid] = bt0[tid] - mean * s;
    }
    __syncthreads();

    for (int l = tid; l < ROWS * O / 2; l += 256) {
        int m = l >> (OSH - 1);
        int c = (l & (O / 2 - 1)) * 2;
        const float2 t1 = *(const float2*)&T1[(size_t)(nb0 + (m >> 4)) * O + c];
        const float2 t2 = *(const float2*)&T2[(size_t)gArr[m] * O + c];
        float v0 = fmaxf((t1.x + t2.x) * sc0[c] + sh0[c], 0.f);
        float v1 = fmaxf((t1.y + t2.y) * sc0[c + 1] + sh0[c + 1], 0.f);
        v2s pr; pr[0] = f2bs(v0); pr[1] = f2bs(v1);
        *(v2s*)&Am[m][c] = pr;
    }
    __syncthreads();

    v4f acc[RT][CPW];
#pragma unroll
    for (int rt = 0; rt < RT; ++rt)
#pragma unroll
        for (int j = 0; j < CPW; ++j)
#pragma unroll
            for (int r = 0; r < 4; ++r) acc[rt][j][r] = 0.f;

#pragma unroll
    for (int k0 = 0; k0 < O; k0 += 32) {
        v8s bv[CPW];
#pragma unroll
        for (int j = 0; j < CPW; ++j) {
            int c = (wave * CPW + j) * 16 + l15;
            bv[j] = *(const v8s*)&W1[(size_t)c * O + k0 + quad * 8];
        }
#pragma unroll
        for (int rt = 0; rt < RT; ++rt) {
            v8s av = *(const v8s*)&Am[rt * 16 + l15][k0 + quad * 8];
#pragma unroll
            for (int j = 0; j < CPW; ++j)
                acc[rt][j] = __builtin_amdgcn_mfma_f32_16x16x32_bf16(av, bv[j], acc[rt][j], 0, 0, 0);
        }
    }
#pragma unroll
    for (int j = 0; j < CPW; ++j) {
        float bb = bias1[(wave * CPW + j) * 16 + l15];
#pragma unroll
        for (int rt = 0; rt < RT; ++rt)
#pragma unroll
            for (int r = 0; r < 4; ++r) acc[rt][j][r] += bb;
    }
#pragma unroll
    for (int j = 0; j < CPW; ++j) {
        int c = (wave * CPW + j) * 16 + l15;
        float s = 0.f, q = 0.f;
#pragma unroll
        for (int rt = 0; rt < RT; ++rt)
#pragma unroll
            for (int r = 0; r < 4; ++r) { float v = acc[rt][j][r]; s += v; q += v * v; }
        s += __shfl_down(s, 32); s += __shfl_down(s, 16);
        q += __shfl_down(q, 32); q += __shfl_down(q, 16);
        if (quad == 0) { atomicAdd(&st1[rep * 512 + c], s); atomicAdd(&st1[rep * 512 + 256 + c], q); }
    }
    __syncthreads();
#pragma unroll
    for (int j = 0; j < CPW; ++j) {
        int c = (wave * CPW + j) * 16 + l15;
#pragma unroll
        for (int rt = 0; rt < RT; ++rt)
#pragma unroll
            for (int r = 0; r < 4; ++r)
                Am[rt * 16 + quad * 4 + r][c] = f2bs(acc[rt][j][r]);
    }
    __syncthreads();
    for (int g = tid; g < ROWS * O / 8; g += 256) {
        int row = g >> (OSH - 3);
        int c8 = (g & (O / 8 - 1)) * 8;
        *(v8s*)&h[(size_t)(e0 + row) * O + c8] = *(const v8s*)&Am[row][c8];
    }
}

// ---------------- gemm2: h -> bn1+relu -> h2 = A1@W2 + b2 -> h (in place) + st2 ------
template<int O, int ROWS>
__global__ __launch_bounds__(256, 6) void gemm2_kernel(
    short* __restrict__ h,
    const short* __restrict__ W2, const float* __restrict__ bias2,
    const float* __restrict__ gm1, const float* __restrict__ bt1,
    const float* __restrict__ st1, float* __restrict__ st2, float inv_n)
{
    constexpr int CPW = O / 64;
    constexpr int RT = ROWS / 16;
    constexpr int OSH = (O == 64) ? 6 : (O == 128 ? 7 : 8);
    constexpr int AP = O + 8;
    constexpr int TPB = 2048 / ROWS;
    __shared__ __align__(16) short Am[ROWS][AP];
    __shared__ float sc1[O], sh1[O];
    const int tid = threadIdx.x;
    const int lane = tid & 63, wave = tid >> 6;
    const int l15 = lane & 15, quad = lane >> 4;
    const int work = swz_tile<TPB>(blockIdx.x);
    const int e0 = work * ROWS;
    const int rep = work & (NREP - 1);

    if (tid < O) {
        float sum, sq;
        fold_stats(st1, tid, sum, sq);
        float mean = sum * inv_n;
        float var = fmaxf(sq * inv_n - mean * mean, 0.f);
        float s = rsqrtf(var + 1e-5f) * gm1[tid];
        sc1[tid] = s; sh1[tid] = bt1[tid] - mean * s;
    }
    __syncthreads();

    for (int g = tid; g < ROWS * O / 8; g += 256) {
        int row = g >> (OSH - 3);
        int c8 = (g & (O / 8 - 1)) * 8;
        v8s hv = *(const v8s*)&h[(size_t)(e0 + row) * O + c8];
        v8s ov;
#pragma unroll
        for (int j = 0; j < 8; ++j) {
            float v = bs2f(hv[j]) * sc1[c8 + j] + sh1[c8 + j];
            ov[j] = f2bs(fmaxf(v, 0.f));
        }
        *(v8s*)&Am[row][c8] = ov;
    }
    __syncthreads();

    v4f acc[RT][CPW];
#pragma unroll
    for (int rt = 0; rt < RT; ++rt)
#pragma unroll
        for (int j = 0; j < CPW; ++j)
#pragma unroll
            for (int r = 0; r < 4; ++r) acc[rt][j][r] = 0.f;

#pragma unroll
    for (int k0 = 0; k0 < O; k0 += 32) {
        v8s bv[CPW];
#pragma unroll
        for (int j = 0; j < CPW; ++j) {
            int c = (wave * CPW + j) * 16 + l15;
            bv[j] = *(const v8s*)&W2[(size_t)c * O + k0 + quad * 8];
        }
#pragma unroll
        for (int rt = 0; rt < RT; ++rt) {
            v8s av = *(const v8s*)&Am[rt * 16 + l15][k0 + quad * 8];
#pragma unroll
            for (int j = 0; j < CPW; ++j)
                acc[rt][j] = __builtin_amdgcn_mfma_f32_16x16x32_bf16(av, bv[j], acc[rt][j], 0, 0, 0);
        }
    }
#pragma unroll
    for (int j = 0; j < CPW; ++j) {
        float bb = bias2[(wave * CPW + j) * 16 + l15];
#pragma unroll
        for (int rt = 0; rt < RT; ++rt)
#pragma unroll
            for (int r = 0; r < 4; ++r) acc[rt][j][r] += bb;
    }
#pragma unroll
    for (int j = 0; j < CPW; ++j) {
        int c = (wave * CPW + j) * 16 + l15;
        float s = 0.f, q = 0.f;
#pragma unroll
        for (int rt = 0; rt < RT; ++rt)
#pragma unroll
            for (int r = 0; r < 4; ++r) { float v = acc[rt][j][r]; s += v; q += v * v; }
        s += __shfl_down(s, 32); s += __shfl_down(s, 16);
        q += __shfl_down(q, 32); q += __shfl_down(q, 16);
        if (quad == 0) { atomicAdd(&st2[rep * 512 + c], s); atomicAdd(&st2[rep * 512 + 256 + c], q); }
    }
    __syncthreads();
#pragma unroll
    for (int j = 0; j < CPW; ++j) {
        int c = (wave * CPW + j) * 16 + l15;
#pragma unroll
        for (int rt = 0; rt < RT; ++rt)
#pragma unroll
            for (int r = 0; r < 4; ++r)
                Am[rt * 16 + quad * 4 + r][c] = f2bs(acc[rt][j][r]);
    }
    __syncthreads();
    for (int g = tid; g < ROWS * O / 8; g += 256) {
        int row = g >> (OSH - 3);
        int c8 = (g & (O / 8 - 1)) * 8;
        *(v8s*)&h[(size_t)(e0 + row) * O + c8] = *(const v8s*)&Am[row][c8];
    }
}

// ---------------- finish: stream h2, bn2+relu, k-mean, skip-concat ----------------
template<int O, int ROWS>
__global__ __launch_bounds__(256) void finish_kernel(
    const short* __restrict__ h,
    const float* __restrict__ st2, const float* __restrict__ gm2, const float* __restrict__ bt2,
    const float* __restrict__ xold, float* __restrict__ xnew, int F, float inv_n)
{
    constexpr int G = 256 / O;
    constexpr int RPG = ROWS / G;
    constexpr int NPG = RPG / 16;
    constexpr int NPB = ROWS / 16;
    constexpr int TPB = 2048 / ROWS;
    const int tid = threadIdx.x;
    const int c = tid & (O - 1);
    const int rg = tid / O;
    const int work = swz_tile<TPB>(blockIdx.x);
    const int e0 = work * ROWS;
    const int nb0 = e0 >> 4;
    float sum, sq;
    fold_stats(st2, c, sum, sq);
    float mean = sum * inv_n;
    float var = fmaxf(sq * inv_n - mean * mean, 0.f);
    float sc = rsqrtf(var + 1e-5f) * gm2[c];
    float sh = bt2[c] - mean * sc;
    float s[NPG];
#pragma unroll
    for (int i = 0; i < NPG; ++i) s[i] = 0.f;
    const int m0 = rg * RPG;
#pragma unroll
    for (int r = 0; r < RPG; ++r) {
        float v = bs2f(h[(size_t)(e0 + m0 + r) * O + c]) * sc + sh;
        s[r >> 4] += fmaxf(v, 0.f);
    }
    const int Cnew = O + F;
#pragma unroll
    for (int i = 0; i < NPG; ++i)
        xnew[(size_t)(nb0 + rg * NPG + i) * Cnew + c] = s[i] * (1.0f / 16.0f);
    for (int l = tid; l < NPB * F; l += 256) {
        int nd = l / F, cc = l - nd * F;
        xnew[(size_t)(nb0 + nd) * Cnew + O + cc] = xold[(size_t)(nb0 + nd) * F + cc];
    }
}

// ---------------- global mean pool ----------------
__global__ __launch_bounds__(256) void pool_kernel(const float* __restrict__ x, float* __restrict__ pooled, int C) {
    int b = blockIdx.x, t = threadIdx.x;
    for (int c = t; c < C; c += 256) {
        float s = 0.f;
        for (int n = 0; n < NN; ++n) s += x[(size_t)(b * NN + n) * C + c];
        pooled[b * C + c] = s * (1.0f / NN);
    }
}

// ---------------- fc1 + fc2 ----------------
__global__ __launch_bounds__(256) void fc_kernel(const float* __restrict__ pooled,
                                                 const float* __restrict__ W1, const float* __restrict__ b1,
                                                 const float* __restrict__ W2, const float* __restrict__ b2,
                                                 float* __restrict__ out, int C) {
    __shared__ float px[451];
    __shared__ float h1[256];
    int b = blockIdx.x, t = threadIdx.x;
    for (int c = t; c < C; c += 256) px[c] = pooled[b * C + c];
    __syncthreads();
    float s = 0.f;
    for (int i = 0; i < C; ++i) s += px[i] * W1[(size_t)i * 256 + t];
    h1[t] = s + b1[t];
    __syncthreads();
    if (t < 5) {
        float s2 = 0.f;
        for (int j = 0; j < 256; ++j) s2 += h1[j] * W2[j * 5 + t];
        out[b * 5 + t] = s2 + b2[t];
    }
}

extern "C" void kernel_launch(void* const* d_in, const int* in_sizes, int n_in,
                              void* d_out, int out_size, void* d_ws, size_t ws_size,
                              hipStream_t stream) {
    const float* xin = (const float*)d_in[0];
    auto Wp = [&](int c, int l) { return (const float*)d_in[1 + c * 12 + l * 4 + 0]; };
    auto Bp = [&](int c, int l) { return (const float*)d_in[1 + c * 12 + l * 4 + 1]; };
    auto Gp = [&](int c, int l) { return (const float*)d_in[1 + c * 12 + l * 4 + 2]; };
    auto Ep = [&](int c, int l) { return (const float*)d_in[1 + c * 12 + l * 4 + 3]; };
    const float* fcW1 = (const float*)d_in[37];
    const float* fcb1 = (const float*)d_in[38];
    const float* fcW2 = (const float*)d_in[39];
    const float* fcb2 = (const float*)d_in[40];

    char* ws = (char*)d_ws;
    size_t off = 0;
    auto alloc = [&](size_t bytes) -> void* {
        void* p = ws + off;
        off += (bytes + 255) & ~(size_t)255;
        return p;
    };
    const int M = M_NODES;
    float* x1     = (float*)alloc((size_t)M * 67 * 4);
    float* x2     = (float*)alloc((size_t)M * 195 * 4);
    float* x3     = (float*)alloc((size_t)M * 451 * 4);
    float* T1     = (float*)alloc((size_t)M * 256 * 4);
    float* T2     = (float*)alloc((size_t)M * 256 * 4);
    int*   idxb   = (int*)alloc((size_t)M * KNN * 4);
    float* stats  = (float*)alloc((size_t)3 * NREP * 512 * 4);
    float* pooled = (float*)alloc((size_t)NB * 451 * 4);
    short* W1b    = (short*)alloc(256 * 256 * 2);
    short* W2b    = (short*)alloc(256 * 256 * 2);
    short* W0d    = (short*)alloc(256 * 224 * 2);
    short* W0b    = (short*)alloc(256 * 224 * 2);
    float* d2buf  = (float*)alloc((size_t)M * NN * 4);
    short* hbuf   = (short*)alloc((size_t)NPOS * 256 * 2);
    (void)in_sizes; (void)n_in; (void)out_size; (void)ws_size;

    float* st0 = stats;
    float* st1 = stats + NREP * 512;
    float* st2 = stats + 2 * NREP * 512;
    const float inv_n = 1.0f / (float)NPOS;

    auto run_conv = [&](const float* xc, float* xn, int F, int D, int O, int c) {
        const int Fpad = (F + 31) & ~31;
        dist_kernel<<<dim3(2, M / 64), 256, 0, stream>>>(xc, F, D, d2buf);
        knn_select_kernel<<<M / 4, 256, 0, stream>>>(d2buf, idxb);
        const int prepN = 3 * NREP * 512 + O * Fpad + 2 * O * O;
        prep_kernel<<<(prepN + 255) / 256, 256, 0, stream>>>(Wp(c, 0), Wp(c, 1), Wp(c, 2),
            W0d, W0b, W1b, W2b, stats, F, Fpad, O);
        auto launch = [&](auto tag) {
            constexpr int OO = decltype(tag)::value;
            constexpr int RR = 8192 / OO;         // 128/64/32 rows per tile
            const int grid = (int)(NPOS / RR);
            node_gemm_mfma<OO><<<M / 64, 256, 0, stream>>>(xc, F, Fpad, W0d, W0b, Bp(c, 0), T1, T2);
            stats0_lds_kernel<OO><<<NB * (OO > 128 ? 2 : 1), 256, 0, stream>>>(T1, T2, idxb, st0);
            gemm1_kernel<OO, RR><<<grid, 256, 0, stream>>>(T1, T2, idxb, W1b, Bp(c, 1),
                Gp(c, 0), Ep(c, 0), st0, st1, hbuf, inv_n);
            gemm2_kernel<OO, RR><<<grid, 256, 0, stream>>>(hbuf, W2b, Bp(c, 2),
                Gp(c, 1), Ep(c, 1), st1, st2, inv_n);
            finish_kernel<OO, RR><<<grid, 256, 0, stream>>>(hbuf, st2, Gp(c, 2), Ep(c, 2),
                xc, xn, F, inv_n);
        };
        if (O == 64)       launch(std::integral_constant<int, 64>{});
        else if (O == 128) launch(std::integral_constant<int, 128>{});
        else               launch(std::integral_constant<int, 256>{});
    };

    run_conv(xin, x1, 3, 2, 64, 0);     // -> x1: C=67
    run_conv(x1, x2, 67, 67, 128, 1);   // -> x2: C=195
    run_conv(x2, x3, 195, 195, 256, 2); // -> x3: C=451
    pool_kernel<<<NB, 256, 0, stream>>>(x3, pooled, 451);
    fc_kernel<<<NB, 256, 0, stream>>>(pooled, fcW1, fcb1, fcW2, fcb2, (float*)d_out, 451);
}

// Round 18
// 874.196 us; speedup vs baseline: 1.9464x; 1.1236x over previous
//
#include <hip/hip_runtime.h>
#include <hip/hip_bf16.h>
#include <type_traits>

typedef __hip_bfloat16 bf16;
typedef short v8s __attribute__((ext_vector_type(8)));
typedef short v2s __attribute__((ext_vector_type(2)));
typedef float v4f __attribute__((ext_vector_type(4)));

__device__ __forceinline__ float b2f(bf16 v) { return __bfloat162float(v); }
__device__ __forceinline__ bf16  f2b(float v) { return __float2bfloat16(v); }
__device__ __forceinline__ short f2bs(float v) {
    bf16 b = f2b(v); short s; __builtin_memcpy(&s, &b, 2); return s;
}
__device__ __forceinline__ float bs2f(short s) {
    bf16 b; __builtin_memcpy(&b, &s, 2); return b2f(b);
}

#define NB 128
#define NN 128
#define KNN 16
#define M_NODES (NB * NN)          // 16384
#define NPOS ((long)M_NODES * KNN) // 262144 edge rows
#define NREP 16                    // stats replicas

__device__ __forceinline__ void fold_stats(const float* __restrict__ st, int c,
                                           float& sum, float& sq) {
    sum = 0.f; sq = 0.f;
#pragma unroll
    for (int r = 0; r < NREP; ++r) { sum += st[r * 512 + c]; sq += st[r * 512 + 256 + c]; }
}

// XCD batch-affinity swizzle. TPB tiles per batch; slot->XCD assumed round-robin.
template<int TPB>
__device__ __forceinline__ int swz_tile(int bid) {
    int xcd = bid & 7;
    int slot = bid >> 3;
    int batch = xcd * 16 + slot / TPB;
    int tile = slot - (slot / TPB) * TPB;
    return batch * TPB + tile;
}

// ---------------- fused prep: zero stats + weight precompute ----------------
__global__ __launch_bounds__(256) void prep_kernel(
    const float* __restrict__ W0, const float* __restrict__ W1, const float* __restrict__ W2,
    short* __restrict__ W0d, short* __restrict__ W0b,
    short* __restrict__ W1b, short* __restrict__ W2b,
    float* __restrict__ stats, int F, int Fpad, int O)
{
    int i = blockIdx.x * 256 + threadIdx.x;
    const int nz = 3 * NREP * 512;
    if (i < nz) { stats[i] = 0.f; return; }
    i -= nz;
    const int n0 = O * Fpad;
    if (i < n0) {
        int c = i / Fpad, k = i - c * Fpad;
        if (k < F) {
            float wt = W0[(size_t)k * O + c];
            float wb = W0[(size_t)(F + k) * O + c];
            W0d[i] = f2bs(wt - wb);
            W0b[i] = f2bs(wb);
        } else { W0d[i] = 0; W0b[i] = 0; }
        return;
    }
    i -= n0;
    const int n1 = O * O;
    if (i < n1) {
        int c = i / O, k = i - c * O;
        W1b[i] = f2bs(W1[(size_t)k * O + c]);
        return;
    }
    i -= n1;
    if (i < n1) {
        int c = i / O, k = i - c * O;
        W2b[i] = f2bs(W2[(size_t)k * O + c]);
    }
}

// ---------------- kNN: d2 tile GEMM with inline norms ----------------
__global__ __launch_bounds__(256) void dist_kernel(const float* __restrict__ x, int C, int D,
                                                   float* __restrict__ d2) {
    __shared__ float As[16][65];
    __shared__ float Bs[16][65];
    const int tid = threadIdx.x;
    const int tx = tid & 15, ty = tid >> 4;
    const int m0 = blockIdx.y * 64;
    const int b  = m0 >> 7;
    const int c0 = blockIdx.x * 64;
    float acc[4][4], rn[4], cn[4];
#pragma unroll
    for (int r = 0; r < 4; ++r) { rn[r] = 0.f; cn[r] = 0.f;
#pragma unroll
        for (int c = 0; c < 4; ++c) acc[r][c] = 0.f; }
    for (int k0 = 0; k0 < D; k0 += 16) {
        for (int l = tid; l < 1024; l += 256) {
            int k = l & 15, m = l >> 4;
            int kk = k0 + k;
            As[k][m] = (kk < D) ? x[(size_t)(m0 + m) * C + kk] : 0.f;
            Bs[k][m] = (kk < D) ? x[(size_t)(b * NN + c0 + m) * C + kk] : 0.f;
        }
        __syncthreads();
        for (int k = 0; k < 16; ++k) {
            float av[4], bv[4];
#pragma unroll
            for (int r = 0; r < 4; ++r) { av[r] = As[k][ty + 16 * r]; rn[r] += av[r] * av[r]; }
#pragma unroll
            for (int c = 0; c < 4; ++c) { bv[c] = Bs[k][tx + 16 * c]; cn[c] += bv[c] * bv[c]; }
#pragma unroll
            for (int r = 0; r < 4; ++r)
#pragma unroll
                for (int c = 0; c < 4; ++c) acc[r][c] += av[r] * bv[c];
        }
        __syncthreads();
    }
#pragma unroll
    for (int r = 0; r < 4; ++r)
#pragma unroll
        for (int c = 0; c < 4; ++c) {
            int m = m0 + ty + 16 * r;
            int jl = c0 + tx + 16 * c;
            int jg = b * NN + jl;
            float v = rn[r] + cn[c] - 2.0f * acc[r][c];
            if (m == jg) v += 1e9f;
            d2[(size_t)m * NN + jl] = v;
        }
}

// ---------------- kNN: wave-per-node top-16 ----------------
__global__ __launch_bounds__(256) void knn_select_kernel(const float* __restrict__ d2,
                                                         int* __restrict__ idx) {
    const int node = blockIdx.x * 4 + (threadIdx.x >> 6);
    const int lane = threadIdx.x & 63;
    const float* row = d2 + (size_t)node * NN;
    float v0 = row[lane], v1 = row[lane + 64];
    int j0 = lane, j1 = lane + 64;
    int myIdx = 0;
#pragma unroll
    for (int k = 0; k < KNN; ++k) {
        float bv; int bj;
        if (v1 < v0 || (v1 == v0 && j1 < j0)) { bv = v1; bj = j1; }
        else                                 { bv = v0; bj = j0; }
#pragma unroll
        for (int off = 32; off; off >>= 1) {
            float ov = __shfl_xor(bv, off);
            int oj = __shfl_xor(bj, off);
            if (ov < bv || (ov == bv && oj < bj)) { bv = ov; bj = oj; }
        }
        if (bj == j0) v0 = 3.0e38f;
        if (bj == j1) v1 = 3.0e38f;
        if (lane == k) myIdx = bj;
    }
    if (lane < KNN) idx[(size_t)node * KNN + lane] = myIdx;
}

// ---------------- MFMA node GEMM: T1 = x@Wd + bias, T2 = x@Wb ----------------
template<int O>
__global__ __launch_bounds__(256, 2) void node_gemm_mfma(
    const float* __restrict__ x, int F, int Fpad,
    const short* __restrict__ Wd, const short* __restrict__ Wb,
    const float* __restrict__ bias,
    float* __restrict__ T1, float* __restrict__ T2)
{
    constexpr int CPW = O / 64;
    __shared__ __align__(16) short Am[64][232];
    const int tid = threadIdx.x;
    const int lane = tid & 63, wave = tid >> 6;
    const int l15 = lane & 15, quad = lane >> 4;
    const int m0 = blockIdx.x * 64;
    for (int l = tid; l < 64 * Fpad; l += 256) {
        int m = l / Fpad, k = l - m * Fpad;
        Am[m][k] = (k < F) ? f2bs(x[(size_t)(m0 + m) * F + k]) : (short)0;
    }
    __syncthreads();
#pragma unroll
    for (int p = 0; p < 2; ++p) {
        const short* __restrict__ Wg = p ? Wb : Wd;
        float* __restrict__ T = p ? T2 : T1;
        v4f acc[4][CPW];
#pragma unroll
        for (int rt = 0; rt < 4; ++rt)
#pragma unroll
            for (int j = 0; j < CPW; ++j)
#pragma unroll
                for (int r = 0; r < 4; ++r) acc[rt][j][r] = 0.f;
        for (int k0 = 0; k0 < Fpad; k0 += 32) {
#pragma unroll
            for (int rt = 0; rt < 4; ++rt) {
                v8s av = *(const v8s*)&Am[rt * 16 + l15][k0 + quad * 8];
#pragma unroll
                for (int j = 0; j < CPW; ++j) {
                    int c = (wave * CPW + j) * 16 + l15;
                    v8s bv = *(const v8s*)&Wg[(size_t)c * Fpad + k0 + quad * 8];
                    acc[rt][j] = __builtin_amdgcn_mfma_f32_16x16x32_bf16(av, bv, acc[rt][j], 0, 0, 0);
                }
            }
        }
#pragma unroll
        for (int j = 0; j < CPW; ++j) {
            int c = (wave * CPW + j) * 16 + l15;
            float bb = p ? 0.f : bias[c];
#pragma unroll
            for (int rt = 0; rt < 4; ++rt)
#pragma unroll
                for (int r = 0; r < 4; ++r)
                    T[(size_t)(m0 + rt * 16 + quad * 4 + r) * O + c] = acc[rt][j][r] + bb;
        }
    }
}

// ---------------- stats0: LDS-staged per-batch ----------------
template<int O>
__global__ __launch_bounds__(256) void stats0_lds_kernel(
    const float* __restrict__ T1, const float* __restrict__ T2,
    const int* __restrict__ idx, float* __restrict__ st0)
{
    constexpr int CH = (O > 128) ? 128 : O;
    constexpr int NG = 256 / CH;
    constexpr int NPG = NN / NG;
    __shared__ float T2s[NN][CH];
    __shared__ int idxs[NN * KNN];
    __shared__ float redS[NG][CH], redQ[NG][CH];
    const int tid = threadIdx.x;
    const int nchunk = O / CH;
    const int b = blockIdx.x / nchunk;
    const int c0 = (blockIdx.x - b * nchunk) * CH;
    const int rep = blockIdx.x & (NREP - 1);

    for (int l = tid; l < NN * CH; l += 256) {
        int n = l / CH, c = l - n * CH;
        T2s[n][c] = T2[(size_t)(b * NN + n) * O + c0 + c];
    }
    for (int l = tid; l < NN * KNN; l += 256) idxs[l] = idx[(size_t)b * NN * KNN + l];
    __syncthreads();

    const int c = tid & (CH - 1);
    const int g = tid / CH;
    float s = 0.f, q = 0.f;
    for (int n = g * NPG; n < (g + 1) * NPG; ++n) {
        float t1 = T1[(size_t)(b * NN + n) * O + c0 + c];
#pragma unroll
        for (int k = 0; k < KNN; ++k) {
            int j = idxs[n * KNN + k];
            float v = t1 + T2s[j][c];
            s += v; q += v * v;
        }
    }
    redS[g][c] = s; redQ[g][c] = q;
    __syncthreads();
    if (g == 0) {
#pragma unroll
        for (int gg = 1; gg < NG; ++gg) { s += redS[gg][c]; q += redQ[gg][c]; }
        atomicAdd(&st0[rep * 512 + c0 + c], s);
        atomicAdd(&st0[rep * 512 + 256 + c0 + c], q);
    }
}

// ========================= column-owned MFMA GEMM kernels ==========================
// ROWS = 16384/O rows per block (constant tile area); wave owns O/4 cols for all rows.

// ---------------- gemm1: A0-build -> h1 = A0@W1 + b1 -> h + st1 ----------------
template<int O, int ROWS>
__global__ __launch_bounds__(256, 4) void gemm1_kernel(
    const float* __restrict__ T1, const float* __restrict__ T2, const int* __restrict__ idx,
    const short* __restrict__ W1, const float* __restrict__ bias1,
    const float* __restrict__ gm0, const float* __restrict__ bt0,
    const float* __restrict__ st0, float* __restrict__ st1,
    short* __restrict__ h, float inv_n)
{
    constexpr int CPW = O / 64;
    constexpr int RT = ROWS / 16;
    constexpr int OSH = (O == 64) ? 6 : (O == 128 ? 7 : 8);
    constexpr int AP = O + 8;
    constexpr int TPB = 2048 / ROWS;
    __shared__ __align__(16) short Am[ROWS][AP];
    __shared__ float sc0[O], sh0[O];
    __shared__ int gArr[ROWS];
    const int tid = threadIdx.x;
    const int lane = tid & 63, wave = tid >> 6;
    const int l15 = lane & 15, quad = lane >> 4;
    const int work = swz_tile<TPB>(blockIdx.x);
    const int e0 = work * ROWS;
    const int nb0 = e0 >> 4;
    const int rep = work & (NREP - 1);

    for (int l = tid; l < ROWS; l += 256) {
        int e = e0 + l;
        int nd = e >> 4;
        gArr[l] = ((nd >> 7) << 7) + idx[e];
    }
    if (tid < O) {
        float sum, sq;
        fold_stats(st0, tid, sum, sq);
        float mean = sum * inv_n;
        float var = fmaxf(sq * inv_n - mean * mean, 0.f);
        float s = rsqrtf(var + 1e-5f) * gm0[tid];
        sc0[tid] = s; sh0[tid] = bt0[tid] - mean * s;
    }
    __syncthreads();

    for (int l = tid; l < ROWS * O / 2; l += 256) {
        int m = l >> (OSH - 1);
        int c = (l & (O / 2 - 1)) * 2;
        const float2 t1 = *(const float2*)&T1[(size_t)(nb0 + (m >> 4)) * O + c];
        const float2 t2 = *(const float2*)&T2[(size_t)gArr[m] * O + c];
        float v0 = fmaxf((t1.x + t2.x) * sc0[c] + sh0[c], 0.f);
        float v1 = fmaxf((t1.y + t2.y) * sc0[c + 1] + sh0[c + 1], 0.f);
        v2s pr; pr[0] = f2bs(v0); pr[1] = f2bs(v1);
        *(v2s*)&Am[m][c] = pr;
    }
    __syncthreads();

    v4f acc[RT][CPW];
#pragma unroll
    for (int rt = 0; rt < RT; ++rt)
#pragma unroll
        for (int j = 0; j < CPW; ++j)
#pragma unroll
            for (int r = 0; r < 4; ++r) acc[rt][j][r] = 0.f;

#pragma unroll
    for (int k0 = 0; k0 < O; k0 += 32) {
        v8s bv[CPW];
#pragma unroll
        for (int j = 0; j < CPW; ++j) {
            int c = (wave * CPW + j) * 16 + l15;
            bv[j] = *(const v8s*)&W1[(size_t)c * O + k0 + quad * 8];
        }
#pragma unroll
        for (int rt = 0; rt < RT; ++rt) {
            v8s av = *(const v8s*)&Am[rt * 16 + l15][k0 + quad * 8];
#pragma unroll
            for (int j = 0; j < CPW; ++j)
                acc[rt][j] = __builtin_amdgcn_mfma_f32_16x16x32_bf16(av, bv[j], acc[rt][j], 0, 0, 0);
        }
    }
#pragma unroll
    for (int j = 0; j < CPW; ++j) {
        float bb = bias1[(wave * CPW + j) * 16 + l15];
#pragma unroll
        for (int rt = 0; rt < RT; ++rt)
#pragma unroll
            for (int r = 0; r < 4; ++r) acc[rt][j][r] += bb;
    }
#pragma unroll
    for (int j = 0; j < CPW; ++j) {
        int c = (wave * CPW + j) * 16 + l15;
        float s = 0.f, q = 0.f;
#pragma unroll
        for (int rt = 0; rt < RT; ++rt)
#pragma unroll
            for (int r = 0; r < 4; ++r) { float v = acc[rt][j][r]; s += v; q += v * v; }
        s += __shfl_down(s, 32); s += __shfl_down(s, 16);
        q += __shfl_down(q, 32); q += __shfl_down(q, 16);
        if (quad == 0) { atomicAdd(&st1[rep * 512 + c], s); atomicAdd(&st1[rep * 512 + 256 + c], q); }
    }
    __syncthreads();
#pragma unroll
    for (int j = 0; j < CPW; ++j) {
        int c = (wave * CPW + j) * 16 + l15;
#pragma unroll
        for (int rt = 0; rt < RT; ++rt)
#pragma unroll
            for (int r = 0; r < 4; ++r)
                Am[rt * 16 + quad * 4 + r][c] = f2bs(acc[rt][j][r]);
    }
    __syncthreads();
    for (int g = tid; g < ROWS * O / 8; g += 256) {
        int row = g >> (OSH - 3);
        int c8 = (g & (O / 8 - 1)) * 8;
        *(v8s*)&h[(size_t)(e0 + row) * O + c8] = *(const v8s*)&Am[row][c8];
    }
}

// ---------------- gemm2: h -> bn1+relu -> h2 = A1@W2 + b2 -> h (in place) + st2 ------
template<int O, int ROWS>
__global__ __launch_bounds__(256, 4) void gemm2_kernel(
    short* __restrict__ h,
    const short* __restrict__ W2, const float* __restrict__ bias2,
    const float* __restrict__ gm1, const float* __restrict__ bt1,
    const float* __restrict__ st1, float* __restrict__ st2, float inv_n)
{
    constexpr int CPW = O / 64;
    constexpr int RT = ROWS / 16;
    constexpr int OSH = (O == 64) ? 6 : (O == 128 ? 7 : 8);
    constexpr int AP = O + 8;
    constexpr int TPB = 2048 / ROWS;
    __shared__ __align__(16) short Am[ROWS][AP];
    __shared__ float sc1[O], sh1[O];
    const int tid = threadIdx.x;
    const int lane = tid & 63, wave = tid >> 6;
    const int l15 = lane & 15, quad = lane >> 4;
    const int work = swz_tile<TPB>(blockIdx.x);
    const int e0 = work * ROWS;
    const int rep = work & (NREP - 1);

    if (tid < O) {
        float sum, sq;
        fold_stats(st1, tid, sum, sq);
        float mean = sum * inv_n;
        float var = fmaxf(sq * inv_n - mean * mean, 0.f);
        float s = rsqrtf(var + 1e-5f) * gm1[tid];
        sc1[tid] = s; sh1[tid] = bt1[tid] - mean * s;
    }
    __syncthreads();

    for (int g = tid; g < ROWS * O / 8; g += 256) {
        int row = g >> (OSH - 3);
        int c8 = (g & (O / 8 - 1)) * 8;
        v8s hv = *(const v8s*)&h[(size_t)(e0 + row) * O + c8];
        v8s ov;
#pragma unroll
        for (int j = 0; j < 8; ++j) {
            float v = bs2f(hv[j]) * sc1[c8 + j] + sh1[c8 + j];
            ov[j] = f2bs(fmaxf(v, 0.f));
        }
        *(v8s*)&Am[row][c8] = ov;
    }
    __syncthreads();

    v4f acc[RT][CPW];
#pragma unroll
    for (int rt = 0; rt < RT; ++rt)
#pragma unroll
        for (int j = 0; j < CPW; ++j)
#pragma unroll
            for (int r = 0; r < 4; ++r) acc[rt][j][r] = 0.f;

#pragma unroll
    for (int k0 = 0; k0 < O; k0 += 32) {
        v8s bv[CPW];
#pragma unroll
        for (int j = 0; j < CPW; ++j) {
            int c = (wave * CPW + j) * 16 + l15;
            bv[j] = *(const v8s*)&W2[(size_t)c * O + k0 + quad * 8];
        }
#pragma unroll
        for (int rt = 0; rt < RT; ++rt) {
            v8s av = *(const v8s*)&Am[rt * 16 + l15][k0 + quad * 8];
#pragma unroll
            for (int j = 0; j < CPW; ++j)
                acc[rt][j] = __builtin_amdgcn_mfma_f32_16x16x32_bf16(av, bv[j], acc[rt][j], 0, 0, 0);
        }
    }
#pragma unroll
    for (int j = 0; j < CPW; ++j) {
        float bb = bias2[(wave * CPW + j) * 16 + l15];
#pragma unroll
        for (int rt = 0; rt < RT; ++rt)
#pragma unroll
            for (int r = 0; r < 4; ++r) acc[rt][j][r] += bb;
    }
#pragma unroll
    for (int j = 0; j < CPW; ++j) {
        int c = (wave * CPW + j) * 16 + l15;
        float s = 0.f, q = 0.f;
#pragma unroll
        for (int rt = 0; rt < RT; ++rt)
#pragma unroll
            for (int r = 0; r < 4; ++r) { float v = acc[rt][j][r]; s += v; q += v * v; }
        s += __shfl_down(s, 32); s += __shfl_down(s, 16);
        q += __shfl_down(q, 32); q += __shfl_down(q, 16);
        if (quad == 0) { atomicAdd(&st2[rep * 512 + c], s); atomicAdd(&st2[rep * 512 + 256 + c], q); }
    }
    __syncthreads();
#pragma unroll
    for (int j = 0; j < CPW; ++j) {
        int c = (wave * CPW + j) * 16 + l15;
#pragma unroll
        for (int rt = 0; rt < RT; ++rt)
#pragma unroll
            for (int r = 0; r < 4; ++r)
                Am[rt * 16 + quad * 4 + r][c] = f2bs(acc[rt][j][r]);
    }
    __syncthreads();
    for (int g = tid; g < ROWS * O / 8; g += 256) {
        int row = g >> (OSH - 3);
        int c8 = (g & (O / 8 - 1)) * 8;
        *(v8s*)&h[(size_t)(e0 + row) * O + c8] = *(const v8s*)&Am[row][c8];
    }
}

// ---------------- finish: stream h2, bn2+relu, k-mean, skip-concat ----------------
template<int O, int ROWS>
__global__ __launch_bounds__(256) void finish_kernel(
    const short* __restrict__ h,
    const float* __restrict__ st2, const float* __restrict__ gm2, const float* __restrict__ bt2,
    const float* __restrict__ xold, float* __restrict__ xnew, int F, float inv_n)
{
    constexpr int G = 256 / O;
    constexpr int RPG = ROWS / G;
    constexpr int NPG = RPG / 16;
    constexpr int NPB = ROWS / 16;
    constexpr int TPB = 2048 / ROWS;
    const int tid = threadIdx.x;
    const int c = tid & (O - 1);
    const int rg = tid / O;
    const int work = swz_tile<TPB>(blockIdx.x);
    const int e0 = work * ROWS;
    const int nb0 = e0 >> 4;
    float sum, sq;
    fold_stats(st2, c, sum, sq);
    float mean = sum * inv_n;
    float var = fmaxf(sq * inv_n - mean * mean, 0.f);
    float sc = rsqrtf(var + 1e-5f) * gm2[c];
    float sh = bt2[c] - mean * sc;
    float s[NPG];
#pragma unroll
    for (int i = 0; i < NPG; ++i) s[i] = 0.f;
    const int m0 = rg * RPG;
#pragma unroll
    for (int r = 0; r < RPG; ++r) {
        float v = bs2f(h[(size_t)(e0 + m0 + r) * O + c]) * sc + sh;
        s[r >> 4] += fmaxf(v, 0.f);
    }
    const int Cnew = O + F;
#pragma unroll
    for (int i = 0; i < NPG; ++i)
        xnew[(size_t)(nb0 + rg * NPG + i) * Cnew + c] = s[i] * (1.0f / 16.0f);
    for (int l = tid; l < NPB * F; l += 256) {
        int nd = l / F, cc = l - nd * F;
        xnew[(size_t)(nb0 + nd) * Cnew + O + cc] = xold[(size_t)(nb0 + nd) * F + cc];
    }
}

// ---------------- global mean pool ----------------
__global__ __launch_bounds__(256) void pool_kernel(const float* __restrict__ x, float* __restrict__ pooled, int C) {
    int b = blockIdx.x, t = threadIdx.x;
    for (int c = t; c < C; c += 256) {
        float s = 0.f;
        for (int n = 0; n < NN; ++n) s += x[(size_t)(b * NN + n) * C + c];
        pooled[b * C + c] = s * (1.0f / NN);
    }
}

// ---------------- fc1 + fc2 ----------------
__global__ __launch_bounds__(256) void fc_kernel(const float* __restrict__ pooled,
                                                 const float* __restrict__ W1, const float* __restrict__ b1,
                                                 const float* __restrict__ W2, const float* __restrict__ b2,
                                                 float* __restrict__ out, int C) {
    __shared__ float px[451];
    __shared__ float h1[256];
    int b = blockIdx.x, t = threadIdx.x;
    for (int c = t; c < C; c += 256) px[c] = pooled[b * C + c];
    __syncthreads();
    float s = 0.f;
    for (int i = 0; i < C; ++i) s += px[i] * W1[(size_t)i * 256 + t];
    h1[t] = s + b1[t];
    __syncthreads();
    if (t < 5) {
        float s2 = 0.f;
        for (int j = 0; j < 256; ++j) s2 += h1[j] * W2[j * 5 + t];
        out[b * 5 + t] = s2 + b2[t];
    }
}

extern "C" void kernel_launch(void* const* d_in, const int* in_sizes, int n_in,
                              void* d_out, int out_size, void* d_ws, size_t ws_size,
                              hipStream_t stream) {
    const float* xin = (const float*)d_in[0];
    auto Wp = [&](int c, int l) { return (const float*)d_in[1 + c * 12 + l * 4 + 0]; };
    auto Bp = [&](int c, int l) { return (const float*)d_in[1 + c * 12 + l * 4 + 1]; };
    auto Gp = [&](int c, int l) { return (const float*)d_in[1 + c * 12 + l * 4 + 2]; };
    auto Ep = [&](int c, int l) { return (const float*)d_in[1 + c * 12 + l * 4 + 3]; };
    const float* fcW1 = (const float*)d_in[37];
    const float* fcb1 = (const float*)d_in[38];
    const float* fcW2 = (const float*)d_in[39];
    const float* fcb2 = (const float*)d_in[40];

    char* ws = (char*)d_ws;
    size_t off = 0;
    auto alloc = [&](size_t bytes) -> void* {
        void* p = ws + off;
        off += (bytes + 255) & ~(size_t)255;
        return p;
    };
    const int M = M_NODES;
    float* x1     = (float*)alloc((size_t)M * 67 * 4);
    float* x2     = (float*)alloc((size_t)M * 195 * 4);
    float* x3     = (float*)alloc((size_t)M * 451 * 4);
    float* T1     = (float*)alloc((size_t)M * 256 * 4);
    float* T2     = (float*)alloc((size_t)M * 256 * 4);
    int*   idxb   = (int*)alloc((size_t)M * KNN * 4);
    float* stats  = (float*)alloc((size_t)3 * NREP * 512 * 4);
    float* pooled = (float*)alloc((size_t)NB * 451 * 4);
    short* W1b    = (short*)alloc(256 * 256 * 2);
    short* W2b    = (short*)alloc(256 * 256 * 2);
    short* W0d    = (short*)alloc(256 * 224 * 2);
    short* W0b    = (short*)alloc(256 * 224 * 2);
    float* d2buf  = (float*)alloc((size_t)M * NN * 4);
    short* hbuf   = (short*)alloc((size_t)NPOS * 256 * 2);
    (void)in_sizes; (void)n_in; (void)out_size; (void)ws_size;

    float* st0 = stats;
    float* st1 = stats + NREP * 512;
    float* st2 = stats + 2 * NREP * 512;
    const float inv_n = 1.0f / (float)NPOS;

    auto run_conv = [&](const float* xc, float* xn, int F, int D, int O, int c) {
        const int Fpad = (F + 31) & ~31;
        dist_kernel<<<dim3(2, M / 64), 256, 0, stream>>>(xc, F, D, d2buf);
        knn_select_kernel<<<M / 4, 256, 0, stream>>>(d2buf, idxb);
        const int prepN = 3 * NREP * 512 + O * Fpad + 2 * O * O;
        prep_kernel<<<(prepN + 255) / 256, 256, 0, stream>>>(Wp(c, 0), Wp(c, 1), Wp(c, 2),
            W0d, W0b, W1b, W2b, stats, F, Fpad, O);
        auto launch = [&](auto tag) {
            constexpr int OO = decltype(tag)::value;
            constexpr int RR = 16384 / OO;        // 256/128/64 rows per tile
            const int grid = (int)(NPOS / RR);
            node_gemm_mfma<OO><<<M / 64, 256, 0, stream>>>(xc, F, Fpad, W0d, W0b, Bp(c, 0), T1, T2);
            stats0_lds_kernel<OO><<<NB * (OO > 128 ? 2 : 1), 256, 0, stream>>>(T1, T2, idxb, st0);
            gemm1_kernel<OO, RR><<<grid, 256, 0, stream>>>(T1, T2, idxb, W1b, Bp(c, 1),
                Gp(c, 0), Ep(c, 0), st0, st1, hbuf, inv_n);
            gemm2_kernel<OO, RR><<<grid, 256, 0, stream>>>(hbuf, W2b, Bp(c, 2),
                Gp(c, 1), Ep(c, 1), st1, st2, inv_n);
            finish_kernel<OO, RR><<<grid, 256, 0, stream>>>(hbuf, st2, Gp(c, 2), Ep(c, 2),
                xc, xn, F, inv_n);
        };
        if (O == 64)       launch(std::integral_constant<int, 64>{});
        else if (O == 128) launch(std::integral_constant<int, 128>{});
        else               launch(std::integral_constant<int, 256>{});
    };

    run_conv(xin, x1, 3, 2, 64, 0);     // -> x1: C=67
    run_conv(x1, x2, 67, 67, 128, 1);   // -> x2: C=195
    run_conv(x2, x3, 195, 195, 256, 2); // -> x3: C=451
    pool_kernel<<<NB, 256, 0, stream>>>(x3, pooled, 451);
    fc_kernel<<<NB, 256, 0, stream>>>(pooled, fcW1, fcb1, fcW2, fcb2, (float*)d_out, 451);
}